// Round 1
// baseline (297.126 us; speedup 1.0000x reference)
//
#include <hip/hip_runtime.h>

// NeurTWs fused position-encoder + merge-layer.
// rows = B*M = 512*2048 = 1,048,576. One thread per row.
// Weights are wave-uniform: indexed only by loop counters + uniform base
// pointers, so LLVM's uniformity analysis turns them into s_load -> SGPR,
// feeding v_fma_f32 directly (1 SGPR operand per VALU instr is legal).
// No LDS at all.

__global__ __launch_bounds__(256, 2) void neurtw_fused(
    const float* __restrict__ pos_table,   // [NUM_KEYS, 4]
    const float* __restrict__ node_feat,   // [NUM_NODES, 64]
    const float* __restrict__ W1,          // [4, 32]
    const float* __restrict__ b1,          // [32]
    const float* __restrict__ W2,          // [32, 32]
    const float* __restrict__ b2,          // [32]
    const float* __restrict__ Wm1,         // [96, 64]
    const float* __restrict__ bm1,         // [64]
    const float* __restrict__ Wm2,         // [64, 1]
    const float* __restrict__ bm2,         // [1]
    const int*   __restrict__ key_idx,     // [B*M]
    const int*   __restrict__ node_idx,    // [B*M]
    float*       __restrict__ out,         // [B*M]
    int rows)
{
    const int row = blockIdx.x * 256 + threadIdx.x;
    if (row >= rows) return;

    const int k  = key_idx[row];
    const int nd = node_idx[row];

    // ---- gather saw encoding: 4 floats, 16B-aligned ----
    const float4 enc = *(const float4*)(pos_table + (size_t)k * 4);
    const float e0 = enc.x, e1 = enc.y, e2 = enc.z, e3 = enc.w;

    // ---- GEMM1: h1 = relu(enc @ W1 + b1), [32] ----
    float h1[32];
    #pragma unroll
    for (int j = 0; j < 32; ++j) {
        float a = fmaf(e3, W1[96 + j],
                  fmaf(e2, W1[64 + j],
                  fmaf(e1, W1[32 + j],
                  fmaf(e0, W1[j], b1[j]))));
        h1[j] = fmaxf(a, 0.0f);
    }

    // ---- GEMM2: pe = h1 @ W2 + b2, [32] ----
    float pe[32];
    #pragma unroll
    for (int j = 0; j < 32; ++j) pe[j] = b2[j];
    #pragma unroll 8
    for (int i = 0; i < 32; ++i) {
        const float hv = h1[i];
        #pragma unroll
        for (int j = 0; j < 32; ++j)
            pe[j] = fmaf(hv, W2[i * 32 + j], pe[j]);
    }

    // ---- gather node features: 64 floats = 16 x float4 ----
    float feat[64];
    const float4* f4 = (const float4*)(node_feat + (size_t)nd * 64);
    #pragma unroll
    for (int i = 0; i < 16; ++i) {
        const float4 v = f4[i];
        feat[4 * i + 0] = v.x;
        feat[4 * i + 1] = v.y;
        feat[4 * i + 2] = v.z;
        feat[4 * i + 3] = v.w;
    }

    // ---- GEMM3: acc = concat(pe, feat) @ Wm1 + bm1, [64] ----
    // outer over K, inner over 64 register accumulators; Wm1 row j is 64
    // consecutive floats -> batched s_load_dwordx16.
    float acc[64];
    #pragma unroll
    for (int c = 0; c < 64; ++c) acc[c] = bm1[c];

    #pragma unroll 4
    for (int j = 0; j < 32; ++j) {
        const float xv = pe[j];
        #pragma unroll
        for (int c = 0; c < 64; ++c)
            acc[c] = fmaf(xv, Wm1[j * 64 + c], acc[c]);
    }
    #pragma unroll 4
    for (int j = 0; j < 64; ++j) {
        const float xv = feat[j];
        #pragma unroll
        for (int c = 0; c < 64; ++c)
            acc[c] = fmaf(xv, Wm1[(32 + j) * 64 + c], acc[c]);
    }

    // ---- GEMM4: z = relu(acc) @ Wm2 + bm2, scalar ----
    float z = bm2[0];
    #pragma unroll
    for (int c = 0; c < 64; ++c)
        z = fmaf(fmaxf(acc[c], 0.0f), Wm2[c], z);

    out[row] = z;
}

extern "C" void kernel_launch(void* const* d_in, const int* in_sizes, int n_in,
                              void* d_out, int out_size, void* d_ws, size_t ws_size,
                              hipStream_t stream) {
    const float* pos_table = (const float*)d_in[0];
    const float* node_feat = (const float*)d_in[1];
    const float* W1        = (const float*)d_in[2];
    const float* b1        = (const float*)d_in[3];
    const float* W2        = (const float*)d_in[4];
    const float* b2        = (const float*)d_in[5];
    const float* Wm1       = (const float*)d_in[6];
    const float* bm1       = (const float*)d_in[7];
    const float* Wm2       = (const float*)d_in[8];
    const float* bm2       = (const float*)d_in[9];
    const int*   key_idx   = (const int*)d_in[10];
    const int*   node_idx  = (const int*)d_in[11];
    float* out = (float*)d_out;

    const int rows = in_sizes[10];            // B*M = 1,048,576
    const int grid = (rows + 255) / 256;
    neurtw_fused<<<grid, 256, 0, stream>>>(
        pos_table, node_feat, W1, b1, W2, b2, Wm1, bm1, Wm2, bm2,
        key_idx, node_idx, out, rows);
}